// Round 4
// baseline (2985.403 us; speedup 1.0000x reference)
//
#include <hip/hip_runtime.h>
#include <math.h>

#define Hdim 256
static const int E_N  = 260640;
static const int NG_N = 65160;
static const int NM_N = 40962;

// Ground-truth f32 fused MLP: out = LN(silu(cat(segs)@W1 + b1)@W2 + b2)*g + b
// [+residual store | atomic scatter]. BM=32 rows/block, 256 threads,
// thread tile = 4 rows x 8 cols (cols = tx*2 + {0,1} + 64*j).
template <int NSEG, bool SCATTER>
__launch_bounds__(256, 2)
__global__ void fused_mlp_f32(
    const float* __restrict__ s0, const float* __restrict__ s1,
    const float* __restrict__ s2, const int* __restrict__ i1,
    const int* __restrict__ i2, int M,
    const float* __restrict__ W1, const float* __restrict__ b1,   // W1 [K1][256]
    const float* __restrict__ W2, const float* __restrict__ b2,   // W2 [256][256]
    const float* __restrict__ gamma, const float* __restrict__ beta,
    const float* __restrict__ residual, float* __restrict__ out,
    float* __restrict__ agg, const int* __restrict__ scat)
{
  constexpr int K1 = NSEG * 256;
  __shared__ float sA[32][36];    // A-tile [row][k within 32] (+pad)
  __shared__ float sB[32][256];   // B-tile (W rows), both layers
  __shared__ float sH[32][256];   // hidden h, then z (LN input)

  const int tid = threadIdx.x;
  const int tx = tid & 31;        // col group
  const int ty = tid >> 5;        // row group 0..7 (rows ty*4..ty*4+3)
  const long blockRow = (long)blockIdx.x * 32;

  // staging role: thread -> (row, float4-part)
  const int srow = tid >> 3;      // 0..31
  const int spart = tid & 7;      // 0..7
  const long grow_s = blockRow + srow;
  const long growc = grow_s < M ? grow_s : (long)(M - 1);
  const float* rp0 = s0 + growc * Hdim;
  const float* rp1 = nullptr;
  const float* rp2 = nullptr;
  if (NSEG >= 2) rp1 = s1 + (long)(i1 ? i1[growc] : (int)growc) * Hdim;
  if (NSEG >= 3) rp2 = s2 + (long)(i2 ? i2[growc] : (int)growc) * Hdim;

  // ---------------- layer 1: cat(segs) @ W1 ----------------
  float acc[4][8] = {};
  for (int ks = 0; ks < K1 / 32; ++ks) {
    __syncthreads();   // previous iteration's sA/sB reads done
    {
      const float* rp = rp0;
      if (NSEG >= 2 && (ks >> 3) == 1) rp = rp1;
      if (NSEG >= 3 && (ks >> 3) == 2) rp = rp2;
      *(float4*)&sA[srow][spart * 4] = *(const float4*)(rp + (ks & 7) * 32 + spart * 4);
      const float* wsrc = W1 + (long)ks * 32 * 256;
      float* bdst = &sB[0][0];
#pragma unroll
      for (int c = 0; c < 8; ++c)
        *(float4*)(bdst + c * 1024 + tid * 4) = *(const float4*)(wsrc + c * 1024 + tid * 4);
    }
    __syncthreads();
#pragma unroll
    for (int kk = 0; kk < 32; ++kk) {
      float av[4];
#pragma unroll
      for (int i = 0; i < 4; ++i) av[i] = sA[ty * 4 + i][kk];
#pragma unroll
      for (int j = 0; j < 4; ++j) {
        const float2 bv = *(const float2*)&sB[kk][tx * 2 + 64 * j];
#pragma unroll
        for (int i = 0; i < 4; ++i) {
          acc[i][j * 2 + 0] = fmaf(av[i], bv.x, acc[i][j * 2 + 0]);
          acc[i][j * 2 + 1] = fmaf(av[i], bv.y, acc[i][j * 2 + 1]);
        }
      }
    }
  }

  // ---------------- bias1 + SiLU -> h (f32 in LDS) ----------------
  float bb[8];
#pragma unroll
  for (int j = 0; j < 4; ++j) {
    const float2 b2v = *(const float2*)&b1[tx * 2 + 64 * j];
    bb[j * 2 + 0] = b2v.x; bb[j * 2 + 1] = b2v.y;
  }
#pragma unroll
  for (int i = 0; i < 4; ++i) {
#pragma unroll
    for (int j = 0; j < 4; ++j) {
      float v0 = acc[i][j * 2 + 0] + bb[j * 2 + 0];
      float v1 = acc[i][j * 2 + 1] + bb[j * 2 + 1];
      float2 hv;
      hv.x = v0 / (1.0f + expf(-v0));
      hv.y = v1 / (1.0f + expf(-v1));
      *(float2*)&sH[ty * 4 + i][tx * 2 + 64 * j] = hv;
    }
  }

  // ---------------- layer 2: h @ W2 ----------------
  float acc2[4][8] = {};
  for (int ks = 0; ks < 8; ++ks) {
    __syncthreads();   // h-writes visible (ks=0); prev sB reads done (ks>0)
    {
      const float* wsrc = W2 + (long)ks * 32 * 256;
      float* bdst = &sB[0][0];
#pragma unroll
      for (int c = 0; c < 8; ++c)
        *(float4*)(bdst + c * 1024 + tid * 4) = *(const float4*)(wsrc + c * 1024 + tid * 4);
    }
    __syncthreads();
#pragma unroll
    for (int kk = 0; kk < 32; ++kk) {
      float av[4];
#pragma unroll
      for (int i = 0; i < 4; ++i) av[i] = sH[ty * 4 + i][ks * 32 + kk];
#pragma unroll
      for (int j = 0; j < 4; ++j) {
        const float2 bv = *(const float2*)&sB[kk][tx * 2 + 64 * j];
#pragma unroll
        for (int i = 0; i < 4; ++i) {
          acc2[i][j * 2 + 0] = fmaf(av[i], bv.x, acc2[i][j * 2 + 0]);
          acc2[i][j * 2 + 1] = fmaf(av[i], bv.y, acc2[i][j * 2 + 1]);
        }
      }
    }
  }
  __syncthreads();   // all sH (h) reads done before z overlays it

  // ---------------- bias2 -> z into sH ----------------
#pragma unroll
  for (int j = 0; j < 4; ++j) {
    const float2 b2v = *(const float2*)&b2[tx * 2 + 64 * j];
    bb[j * 2 + 0] = b2v.x; bb[j * 2 + 1] = b2v.y;
  }
#pragma unroll
  for (int i = 0; i < 4; ++i) {
#pragma unroll
    for (int j = 0; j < 4; ++j) {
      float2 zv;
      zv.x = acc2[i][j * 2 + 0] + bb[j * 2 + 0];
      zv.y = acc2[i][j * 2 + 1] + bb[j * 2 + 1];
      *(float2*)&sH[ty * 4 + i][tx * 2 + 64 * j] = zv;
    }
  }
  __syncthreads();

  // ---------------- LayerNorm + epilogue (wave w: rows w*8..w*8+7) ----------------
  const int w = tid >> 6;
  const int l = tid & 63;
  const float4 gm = *(const float4*)&gamma[l * 4];
  const float4 bt = *(const float4*)&beta[l * 4];
  for (int rr = 0; rr < 8; ++rr) {
    const int row = w * 8 + rr;
    const long grow = blockRow + row;
    const float4 v = *(const float4*)&sH[row][l * 4];
    // pass 1: mean
    float s = v.x + v.y + v.z + v.w;
#pragma unroll
    for (int off = 32; off >= 1; off >>= 1) s += __shfl_xor(s, off, 64);
    const float mu = s * (1.0f / 256.0f);
    // pass 2: variance of deviations (stable, matches reference structure)
    const float dx = v.x - mu, dy = v.y - mu, dz = v.z - mu, dw = v.w - mu;
    float sq = dx * dx + dy * dy + dz * dz + dw * dw;
#pragma unroll
    for (int off = 32; off >= 1; off >>= 1) sq += __shfl_xor(sq, off, 64);
    const float var = sq * (1.0f / 256.0f);
    const float rstd = 1.0f / sqrtf(var + 1e-5f);
    float4 y;
    y.x = dx * rstd * gm.x + bt.x;
    y.y = dy * rstd * gm.y + bt.y;
    y.z = dz * rstd * gm.z + bt.z;
    y.w = dw * rstd * gm.w + bt.w;
    if (grow < M) {
      if constexpr (SCATTER) {
        const int d = scat[grow];
        float* ap = agg + (long)d * Hdim + l * 4;
        atomicAdd(ap + 0, y.x);
        atomicAdd(ap + 1, y.y);
        atomicAdd(ap + 2, y.z);
        atomicAdd(ap + 3, y.w);
      } else {
        const long o = grow * Hdim + l * 4;
        if (residual) {
          const float4 r4 = *(const float4*)&residual[o];
          y.x += r4.x; y.y += r4.y; y.z += r4.z; y.w += r4.w;
        }
        *(float4*)&out[o] = y;
      }
    }
  }
}

extern "C" void kernel_launch(void* const* d_in, const int* in_sizes, int n_in,
                              void* d_out, int out_size, void* d_ws, size_t ws_size,
                              hipStream_t stream) {
  const float* g2m   = (const float*)d_in[0];
  const float* gridf = (const float*)d_in[1];
  const float* meshf = (const float*)d_in[2];
  const int*   src   = (const int*)d_in[3];
  const int*   dst   = (const int*)d_in[4];
  const float* eW1 = (const float*)d_in[5];  const float* eb1 = (const float*)d_in[6];
  const float* eW2 = (const float*)d_in[7];  const float* eb2 = (const float*)d_in[8];
  const float* eg  = (const float*)d_in[9];  const float* ebt = (const float*)d_in[10];
  const float* sW1 = (const float*)d_in[11]; const float* sb1 = (const float*)d_in[12];
  const float* sW2 = (const float*)d_in[13]; const float* sb2 = (const float*)d_in[14];
  const float* sg  = (const float*)d_in[15]; const float* sbt = (const float*)d_in[16];
  const float* dW1 = (const float*)d_in[17]; const float* db1 = (const float*)d_in[18];
  const float* dW2 = (const float*)d_in[19]; const float* db2 = (const float*)d_in[20];
  const float* dg  = (const float*)d_in[21]; const float* dbt = (const float*)d_in[22];

  float* out_grid = (float*)d_out;
  float* out_mesh = out_grid + (long)NG_N * Hdim;  // doubles as agg accumulator

  // zero the agg accumulator (mesh output region)
  (void)hipMemsetAsync(out_mesh, 0, (size_t)NM_N * Hdim * sizeof(float), stream);

  // edge MLP: cat[g2m, grid[src], mesh[dst]] -> LN -> atomic scatter into agg
  fused_mlp_f32<3, true><<<(E_N + 31) / 32, 256, 0, stream>>>(
      g2m, gridf, meshf, src, dst, E_N,
      eW1, eb1, eW2, eb2, eg, ebt,
      nullptr, nullptr, out_mesh, dst);

  // grid MLP: grid_new = grid + MLP(grid)
  fused_mlp_f32<1, false><<<(NG_N + 31) / 32, 256, 0, stream>>>(
      gridf, nullptr, nullptr, nullptr, nullptr, NG_N,
      sW1, sb1, sW2, sb2, sg, sbt,
      gridf, out_grid, nullptr, nullptr);

  // mesh MLP: mesh_new = mesh + MLP(cat[agg, mesh]) (reads own agg rows, then overwrites)
  fused_mlp_f32<2, false><<<(NM_N + 31) / 32, 256, 0, stream>>>(
      out_mesh, meshf, nullptr, nullptr, nullptr, NM_N,
      dW1, db1, dW2, db2, dg, dbt,
      meshf, out_mesh, nullptr, nullptr);
}

// Round 5
// 1933.938 us; speedup vs baseline: 1.5437x; 1.5437x over previous
//
#include <hip/hip_runtime.h>
#include <math.h>

#define Hdim 256
static const int E_N  = 260640;
static const int NG_N = 65160;
static const int NM_N = 40962;

typedef __attribute__((ext_vector_type(8))) __bf16 bf16x8;
typedef __attribute__((ext_vector_type(8))) unsigned short u16x8;
typedef __attribute__((ext_vector_type(4))) float f32x4;

__device__ __forceinline__ unsigned short f2bf(float f) {
  unsigned u = __float_as_uint(f);
  u = (u + 0x7FFFu + ((u >> 16) & 1u)) >> 16;
  return (unsigned short)u;
}
__device__ __forceinline__ float bf2f(unsigned short h) {
  return __uint_as_float((unsigned)h << 16);
}
struct BfPair { unsigned short hi, lo; };
__device__ __forceinline__ BfPair split2(float f) {
  BfPair r;
  r.hi = f2bf(f);
  r.lo = f2bf(f - bf2f(r.hi));
  return r;
}

// W [K][N] f32 -> WT_hi/WT_lo [N][K] bf16 split (one-shot pre-pass)
__global__ void wtrans_kernel(const float* __restrict__ W,
                              unsigned short* __restrict__ WThi,
                              unsigned short* __restrict__ WTlo, int K, int N) {
  int i = blockIdx.x * 256 + threadIdx.x;
  if (i >= K * N) return;
  int n = i / K;
  int k = i - n * K;
  BfPair p = split2(W[(long)k * N + n]);
  WThi[i] = p.hi;
  WTlo[i] = p.lo;
}

// ============================================================================
// Edge kernel: MFMA split-bf16 3-product.
// BM=64 rows/block, 4 waves; wave w owns cols [w*64, w*64+64).
// out = LN(silu(cat(g2m,grid[src],mesh[dst])@W1+b1)@W2+b2) -> atomic scatter
// ============================================================================
struct ESmemA {
  unsigned short ahi[4][64][8];  // [kgroup][row][8] (16 KB)
  unsigned short alo[4][64][8];
};
struct ESmemH {
  unsigned short hhi[64 * 256];  // XOR-swizzled (64 KB total with hlo)
  unsigned short hlo[64 * 256];
};
union ESmem {
  ESmemA a;
  ESmemH h;
  float ln[64 * 256];
};

__global__ __launch_bounds__(256, 2)
void edge_mlp_mfma(const float* __restrict__ g2m, const float* __restrict__ gridf,
                   const float* __restrict__ meshf, const int* __restrict__ src,
                   const int* __restrict__ dst, int M,
                   const unsigned short* __restrict__ W1Th, const unsigned short* __restrict__ W1Tl,
                   const float* __restrict__ b1,
                   const unsigned short* __restrict__ W2Th, const unsigned short* __restrict__ W2Tl,
                   const float* __restrict__ b2,
                   const float* __restrict__ gamma, const float* __restrict__ beta,
                   float* __restrict__ agg) {
  constexpr int K1 = 768;
  __shared__ ESmem sm;

  const int tid = threadIdx.x;
  const int w = tid >> 6;
  const int l = tid & 63;
  const int lr = l & 15;
  const int lg = l >> 4;
  const int colbase = w * 64 + lr;
  const long blockRow = (long)blockIdx.x * 64;

  // staging role: (kgroup = w, row = l)
  const long grow_s = blockRow + l;
  const long growc = grow_s < M ? grow_s : (long)(M - 1);
  const float* rp0 = g2m + growc * Hdim;
  const float* rp1 = gridf + (long)src[growc] * Hdim;
  const float* rp2 = meshf + (long)dst[growc] * Hdim;

  // ---------------- layer 1: cat @ W1 (3-product) ----------------
  f32x4 acc[4][4] = {};
  for (int ks = 0; ks < K1 / 32; ++ks) {
    const int seg = ks >> 3;
    const float* rp = seg == 0 ? rp0 : (seg == 1 ? rp1 : rp2);
    __syncthreads();  // prev iteration's A reads done
    {
      const float* p = rp + (ks & 7) * 32 + w * 8;
      float4 x = *(const float4*)p;
      float4 y = *(const float4*)(p + 4);
      float in[8] = {x.x, x.y, x.z, x.w, y.x, y.y, y.z, y.w};
      u16x8 th, tl;
#pragma unroll
      for (int j = 0; j < 8; ++j) {
        BfPair pr = split2(in[j]);
        th[j] = pr.hi;
        tl[j] = pr.lo;
      }
      *(u16x8*)&sm.a.ahi[w][l][0] = th;
      *(u16x8*)&sm.a.alo[w][l][0] = tl;
    }
    __syncthreads();
    bf16x8 ah[4], al[4], bh[4], bl[4];
#pragma unroll
    for (int rb = 0; rb < 4; ++rb) {
      ah[rb] = *(const bf16x8*)&sm.a.ahi[lg][rb * 16 + lr][0];
      al[rb] = *(const bf16x8*)&sm.a.alo[lg][rb * 16 + lr][0];
    }
#pragma unroll
    for (int n = 0; n < 4; ++n) {
      const long off = (long)(colbase + n * 16) * K1 + ks * 32 + lg * 8;
      bh[n] = *(const bf16x8*)(W1Th + off);
      bl[n] = *(const bf16x8*)(W1Tl + off);
    }
#pragma unroll
    for (int rb = 0; rb < 4; ++rb)
#pragma unroll
      for (int n = 0; n < 4; ++n) {
        acc[rb][n] = __builtin_amdgcn_mfma_f32_16x16x32_bf16(ah[rb], bh[n], acc[rb][n], 0, 0, 0);
        acc[rb][n] = __builtin_amdgcn_mfma_f32_16x16x32_bf16(ah[rb], bl[n], acc[rb][n], 0, 0, 0);
        acc[rb][n] = __builtin_amdgcn_mfma_f32_16x16x32_bf16(al[rb], bh[n], acc[rb][n], 0, 0, 0);
      }
  }
  __syncthreads();  // ALL waves' A reads done before h overlays sm.a

  // ---------------- bias1 + SiLU -> h (split bf16, swizzled) ----------------
  float bb1[4];
#pragma unroll
  for (int n = 0; n < 4; ++n) bb1[n] = b1[colbase + n * 16];
#pragma unroll
  for (int rb = 0; rb < 4; ++rb) {
#pragma unroll
    for (int n = 0; n < 4; ++n) {
      const int col = colbase + n * 16;
#pragma unroll
      for (int r = 0; r < 4; ++r) {
        const int row = rb * 16 + lg * 4 + r;
        float v = acc[rb][n][r] + bb1[n];
        v = v / (1.0f + expf(-v));  // accurate SiLU (R4-verified)
        BfPair pr = split2(v);
        const int addr = row * 256 + (col ^ ((row & 7) << 3));
        sm.h.hhi[addr] = pr.hi;
        sm.h.hlo[addr] = pr.lo;
      }
    }
  }
  __syncthreads();

  // ---------------- layer 2: h @ W2 (3-product) ----------------
  f32x4 acc2[4][4] = {};
#pragma unroll
  for (int ks = 0; ks < 8; ++ks) {
    bf16x8 ah[4], al[4], bh[4], bl[4];
#pragma unroll
    for (int rb = 0; rb < 4; ++rb) {
      const int row = rb * 16 + lr;
      const int addr = row * 256 + (((ks * 4 + lg) * 8) ^ ((row & 7) << 3));
      ah[rb] = *(const bf16x8*)&sm.h.hhi[addr];
      al[rb] = *(const bf16x8*)&sm.h.hlo[addr];
    }
#pragma unroll
    for (int n = 0; n < 4; ++n) {
      const long off = (long)(colbase + n * 16) * 256 + ks * 32 + lg * 8;
      bh[n] = *(const bf16x8*)(W2Th + off);
      bl[n] = *(const bf16x8*)(W2Tl + off);
    }
#pragma unroll
    for (int rb = 0; rb < 4; ++rb)
#pragma unroll
      for (int n = 0; n < 4; ++n) {
        acc2[rb][n] = __builtin_amdgcn_mfma_f32_16x16x32_bf16(ah[rb], bh[n], acc2[rb][n], 0, 0, 0);
        acc2[rb][n] = __builtin_amdgcn_mfma_f32_16x16x32_bf16(ah[rb], bl[n], acc2[rb][n], 0, 0, 0);
        acc2[rb][n] = __builtin_amdgcn_mfma_f32_16x16x32_bf16(al[rb], bh[n], acc2[rb][n], 0, 0, 0);
      }
  }
  __syncthreads();  // all h reads done before ln overlays

  // ---------------- bias2 -> ln scratch ----------------
  float bb2[4];
#pragma unroll
  for (int n = 0; n < 4; ++n) bb2[n] = b2[colbase + n * 16];
#pragma unroll
  for (int rb = 0; rb < 4; ++rb)
#pragma unroll
    for (int n = 0; n < 4; ++n)
#pragma unroll
      for (int r = 0; r < 4; ++r)
        sm.ln[(rb * 16 + lg * 4 + r) * 256 + colbase + n * 16] = acc2[rb][n][r] + bb2[n];
  __syncthreads();

  // ---------------- LayerNorm (two-pass, R4-verified) + scatter ----------------
  const float4 gm = *(const float4*)&gamma[l * 4];
  const float4 bt = *(const float4*)&beta[l * 4];
  for (int rr = 0; rr < 16; ++rr) {
    const int row = w * 16 + rr;
    const long grow = blockRow + row;
    const float4 v = *(const float4*)&sm.ln[row * 256 + l * 4];
    float s = v.x + v.y + v.z + v.w;
#pragma unroll
    for (int off = 32; off >= 1; off >>= 1) s += __shfl_xor(s, off, 64);
    const float mu = s * (1.0f / 256.0f);
    const float dx = v.x - mu, dy = v.y - mu, dz = v.z - mu, dw = v.w - mu;
    float sq = dx * dx + dy * dy + dz * dz + dw * dw;
#pragma unroll
    for (int off = 32; off >= 1; off >>= 1) sq += __shfl_xor(sq, off, 64);
    const float var = sq * (1.0f / 256.0f);
    const float rstd = 1.0f / sqrtf(var + 1e-5f);
    if (grow < M) {
      const int d = dst[grow];
      float* ap = agg + (long)d * Hdim + l * 4;
      atomicAdd(ap + 0, dx * rstd * gm.x + bt.x);
      atomicAdd(ap + 1, dy * rstd * gm.y + bt.y);
      atomicAdd(ap + 2, dz * rstd * gm.z + bt.z);
      atomicAdd(ap + 3, dw * rstd * gm.w + bt.w);
    }
  }
}

// ============================================================================
// R4-verified f32 fused MLP (grid / mesh node paths)
// ============================================================================
template <int NSEG, bool SCATTER>
__launch_bounds__(256, 2)
__global__ void fused_mlp_f32(
    const float* __restrict__ s0, const float* __restrict__ s1,
    const float* __restrict__ s2, const int* __restrict__ i1,
    const int* __restrict__ i2, int M,
    const float* __restrict__ W1, const float* __restrict__ b1,
    const float* __restrict__ W2, const float* __restrict__ b2,
    const float* __restrict__ gamma, const float* __restrict__ beta,
    const float* __restrict__ residual, float* __restrict__ out,
    float* __restrict__ agg, const int* __restrict__ scat)
{
  constexpr int K1 = NSEG * 256;
  __shared__ float sA[32][36];
  __shared__ float sB[32][256];
  __shared__ float sH[32][256];

  const int tid = threadIdx.x;
  const int tx = tid & 31;
  const int ty = tid >> 5;
  const long blockRow = (long)blockIdx.x * 32;

  const int srow = tid >> 3;
  const int spart = tid & 7;
  const long grow_s = blockRow + srow;
  const long growc = grow_s < M ? grow_s : (long)(M - 1);
  const float* rp0 = s0 + growc * Hdim;
  const float* rp1 = nullptr;
  const float* rp2 = nullptr;
  if (NSEG >= 2) rp1 = s1 + (long)(i1 ? i1[growc] : (int)growc) * Hdim;
  if (NSEG >= 3) rp2 = s2 + (long)(i2 ? i2[growc] : (int)growc) * Hdim;

  float acc[4][8] = {};
  for (int ks = 0; ks < K1 / 32; ++ks) {
    __syncthreads();
    {
      const float* rp = rp0;
      if (NSEG >= 2 && (ks >> 3) == 1) rp = rp1;
      if (NSEG >= 3 && (ks >> 3) == 2) rp = rp2;
      *(float4*)&sA[srow][spart * 4] = *(const float4*)(rp + (ks & 7) * 32 + spart * 4);
      const float* wsrc = W1 + (long)ks * 32 * 256;
      float* bdst = &sB[0][0];
#pragma unroll
      for (int c = 0; c < 8; ++c)
        *(float4*)(bdst + c * 1024 + tid * 4) = *(const float4*)(wsrc + c * 1024 + tid * 4);
    }
    __syncthreads();
#pragma unroll
    for (int kk = 0; kk < 32; ++kk) {
      float av[4];
#pragma unroll
      for (int i = 0; i < 4; ++i) av[i] = sA[ty * 4 + i][kk];
#pragma unroll
      for (int j = 0; j < 4; ++j) {
        const float2 bv = *(const float2*)&sB[kk][tx * 2 + 64 * j];
#pragma unroll
        for (int i = 0; i < 4; ++i) {
          acc[i][j * 2 + 0] = fmaf(av[i], bv.x, acc[i][j * 2 + 0]);
          acc[i][j * 2 + 1] = fmaf(av[i], bv.y, acc[i][j * 2 + 1]);
        }
      }
    }
  }

  float bb[8];
#pragma unroll
  for (int j = 0; j < 4; ++j) {
    const float2 b2v = *(const float2*)&b1[tx * 2 + 64 * j];
    bb[j * 2 + 0] = b2v.x; bb[j * 2 + 1] = b2v.y;
  }
#pragma unroll
  for (int i = 0; i < 4; ++i) {
#pragma unroll
    for (int j = 0; j < 4; ++j) {
      float v0 = acc[i][j * 2 + 0] + bb[j * 2 + 0];
      float v1 = acc[i][j * 2 + 1] + bb[j * 2 + 1];
      float2 hv;
      hv.x = v0 / (1.0f + expf(-v0));
      hv.y = v1 / (1.0f + expf(-v1));
      *(float2*)&sH[ty * 4 + i][tx * 2 + 64 * j] = hv;
    }
  }

  float acc2[4][8] = {};
  for (int ks = 0; ks < 8; ++ks) {
    __syncthreads();
    {
      const float* wsrc = W2 + (long)ks * 32 * 256;
      float* bdst = &sB[0][0];
#pragma unroll
      for (int c = 0; c < 8; ++c)
        *(float4*)(bdst + c * 1024 + tid * 4) = *(const float4*)(wsrc + c * 1024 + tid * 4);
    }
    __syncthreads();
#pragma unroll
    for (int kk = 0; kk < 32; ++kk) {
      float av[4];
#pragma unroll
      for (int i = 0; i < 4; ++i) av[i] = sH[ty * 4 + i][ks * 32 + kk];
#pragma unroll
      for (int j = 0; j < 4; ++j) {
        const float2 bv = *(const float2*)&sB[kk][tx * 2 + 64 * j];
#pragma unroll
        for (int i = 0; i < 4; ++i) {
          acc2[i][j * 2 + 0] = fmaf(av[i], bv.x, acc2[i][j * 2 + 0]);
          acc2[i][j * 2 + 1] = fmaf(av[i], bv.y, acc2[i][j * 2 + 1]);
        }
      }
    }
  }
  __syncthreads();

#pragma unroll
  for (int j = 0; j < 4; ++j) {
    const float2 b2v = *(const float2*)&b2[tx * 2 + 64 * j];
    bb[j * 2 + 0] = b2v.x; bb[j * 2 + 1] = b2v.y;
  }
#pragma unroll
  for (int i = 0; i < 4; ++i) {
#pragma unroll
    for (int j = 0; j < 4; ++j) {
      float2 zv;
      zv.x = acc2[i][j * 2 + 0] + bb[j * 2 + 0];
      zv.y = acc2[i][j * 2 + 1] + bb[j * 2 + 1];
      *(float2*)&sH[ty * 4 + i][tx * 2 + 64 * j] = zv;
    }
  }
  __syncthreads();

  const int w = tid >> 6;
  const int l = tid & 63;
  const float4 gm = *(const float4*)&gamma[l * 4];
  const float4 bt = *(const float4*)&beta[l * 4];
  for (int rr = 0; rr < 8; ++rr) {
    const int row = w * 8 + rr;
    const long grow = blockRow + row;
    const float4 v = *(const float4*)&sH[row][l * 4];
    float s = v.x + v.y + v.z + v.w;
#pragma unroll
    for (int off = 32; off >= 1; off >>= 1) s += __shfl_xor(s, off, 64);
    const float mu = s * (1.0f / 256.0f);
    const float dx = v.x - mu, dy = v.y - mu, dz = v.z - mu, dw = v.w - mu;
    float sq = dx * dx + dy * dy + dz * dz + dw * dw;
#pragma unroll
    for (int off = 32; off >= 1; off >>= 1) sq += __shfl_xor(sq, off, 64);
    const float var = sq * (1.0f / 256.0f);
    const float rstd = 1.0f / sqrtf(var + 1e-5f);
    float4 y;
    y.x = dx * rstd * gm.x + bt.x;
    y.y = dy * rstd * gm.y + bt.y;
    y.z = dz * rstd * gm.z + bt.z;
    y.w = dw * rstd * gm.w + bt.w;
    if (grow < M) {
      if constexpr (SCATTER) {
        const int d = scat[grow];
        float* ap = agg + (long)d * Hdim + l * 4;
        atomicAdd(ap + 0, y.x);
        atomicAdd(ap + 1, y.y);
        atomicAdd(ap + 2, y.z);
        atomicAdd(ap + 3, y.w);
      } else {
        const long o = grow * Hdim + l * 4;
        if (residual) {
          const float4 r4 = *(const float4*)&residual[o];
          y.x += r4.x; y.y += r4.y; y.z += r4.z; y.w += r4.w;
        }
        *(float4*)&out[o] = y;
      }
    }
  }
}

extern "C" void kernel_launch(void* const* d_in, const int* in_sizes, int n_in,
                              void* d_out, int out_size, void* d_ws, size_t ws_size,
                              hipStream_t stream) {
  const float* g2m   = (const float*)d_in[0];
  const float* gridf = (const float*)d_in[1];
  const float* meshf = (const float*)d_in[2];
  const int*   src   = (const int*)d_in[3];
  const int*   dst   = (const int*)d_in[4];
  const float* eW1 = (const float*)d_in[5];  const float* eb1 = (const float*)d_in[6];
  const float* eW2 = (const float*)d_in[7];  const float* eb2 = (const float*)d_in[8];
  const float* eg  = (const float*)d_in[9];  const float* ebt = (const float*)d_in[10];
  const float* sW1 = (const float*)d_in[11]; const float* sb1 = (const float*)d_in[12];
  const float* sW2 = (const float*)d_in[13]; const float* sb2 = (const float*)d_in[14];
  const float* sg  = (const float*)d_in[15]; const float* sbt = (const float*)d_in[16];
  const float* dW1 = (const float*)d_in[17]; const float* db1 = (const float*)d_in[18];
  const float* dW2 = (const float*)d_in[19]; const float* db2 = (const float*)d_in[20];
  const float* dg  = (const float*)d_in[21]; const float* dbt = (const float*)d_in[22];

  float* out_grid = (float*)d_out;
  float* out_mesh = out_grid + (long)NG_N * Hdim;  // doubles as agg accumulator

  // split-bf16 transposed edge weights in workspace (~1 MB)
  unsigned short* p = (unsigned short*)d_ws;
  unsigned short* eW1Th = p; p += 768 * 256;  unsigned short* eW1Tl = p; p += 768 * 256;
  unsigned short* eW2Th = p; p += 256 * 256;  unsigned short* eW2Tl = p; p += 256 * 256;

  wtrans_kernel<<<(768 * 256 + 255) / 256, 256, 0, stream>>>(eW1, eW1Th, eW1Tl, 768, 256);
  wtrans_kernel<<<(256 * 256 + 255) / 256, 256, 0, stream>>>(eW2, eW2Th, eW2Tl, 256, 256);

  // zero the agg accumulator (mesh output region)
  (void)hipMemsetAsync(out_mesh, 0, (size_t)NM_N * Hdim * sizeof(float), stream);

  // edge MLP (MFMA split-bf16): scatter into agg
  edge_mlp_mfma<<<(E_N + 63) / 64, 256, 0, stream>>>(
      g2m, gridf, meshf, src, dst, E_N,
      eW1Th, eW1Tl, eb1, eW2Th, eW2Tl, eb2, eg, ebt, out_mesh);

  // grid MLP (f32, verified): grid_new = grid + MLP(grid)
  fused_mlp_f32<1, false><<<(NG_N + 31) / 32, 256, 0, stream>>>(
      gridf, nullptr, nullptr, nullptr, nullptr, NG_N,
      sW1, sb1, sW2, sb2, sg, sbt,
      gridf, out_grid, nullptr, nullptr);

  // mesh MLP (f32, verified): mesh_new = mesh + MLP(cat[agg, mesh])
  fused_mlp_f32<2, false><<<(NM_N + 31) / 32, 256, 0, stream>>>(
      out_mesh, meshf, nullptr, nullptr, nullptr, NM_N,
      dW1, db1, dW2, db2, dg, dbt,
      meshf, out_mesh, nullptr, nullptr);
}

// Round 6
// 1773.406 us; speedup vs baseline: 1.6834x; 1.0905x over previous
//
#include <hip/hip_runtime.h>
#include <math.h>

#define Hdim 256
static const int E_N  = 260640;
static const int NG_N = 65160;
static const int NM_N = 40962;

typedef __attribute__((ext_vector_type(8))) __bf16 bf16x8;
typedef __attribute__((ext_vector_type(8))) unsigned short u16x8;
typedef __attribute__((ext_vector_type(4))) float f32x4;

__device__ __forceinline__ unsigned short f2bf(float f) {
  unsigned u = __float_as_uint(f);
  u = (u + 0x7FFFu + ((u >> 16) & 1u)) >> 16;
  return (unsigned short)u;
}
__device__ __forceinline__ float bf2f(unsigned short h) {
  return __uint_as_float((unsigned)h << 16);
}
struct BfPair { unsigned short hi, lo; };
__device__ __forceinline__ BfPair split2(float f) {
  BfPair r;
  r.hi = f2bf(f);
  r.lo = f2bf(f - bf2f(r.hi));
  return r;
}
// full-rank swizzle: spreads the 4 lane-groups AND 4 regs across all 32 banks
__device__ __forceinline__ int hswz(int row) {
  return ((row & 7) << 3) ^ (((row >> 2) & 3) << 4);
}

#define GLOAD16(gp, lp)                                                        \
  __builtin_amdgcn_global_load_lds(                                           \
      (const __attribute__((address_space(1))) void*)(gp),                    \
      (__attribute__((address_space(3))) void*)(lp), 16, 0, 0)

// W [K][N] f32 -> WT_hi/WT_lo [N][K] bf16 split (one-shot pre-pass)
__global__ void wtrans_kernel(const float* __restrict__ W,
                              unsigned short* __restrict__ WThi,
                              unsigned short* __restrict__ WTlo, int K, int N) {
  int i = blockIdx.x * 256 + threadIdx.x;
  if (i >= K * N) return;
  int n = i / K;
  int k = i - n * K;
  BfPair p = split2(W[(long)k * N + n]);
  WThi[i] = p.hi;
  WTlo[i] = p.lo;
}

template <bool HLO>
struct SM {
  unsigned short ahi[4][64][8];         // A chunks [kgroup][row][8]   4 KB
  unsigned short alo[4][64][8];         //                             4 KB
  unsigned short bph[4][2064];          // B planes [kgroup][col*8+..] 16.5 KB (padded)
  unsigned short bpl[4][2064];          //                             16.5 KB
  unsigned short hh[64 * 256];          // h hi, swizzled              32 KB
  unsigned short hl[HLO ? 64 * 256 : 8];// h lo (grid only)            32 KB / -
  float lnp[4][64][2];                  // LN partials [wave][row][s,q] 2 KB
};

// out = LN(silu(cat(segs)@W1+b1)@W2+b2)*g+b  [+residual store | atomic scatter]
// Split-bf16 MFMA: layer1 3-product; layer2 2-product (3 if HLO).
template <int NSEG, bool SCATTER, bool HLO>
__launch_bounds__(256, 2)
__global__ void mlp_mfma(
    const float* s0, const float* s1, const float* s2,
    const int* __restrict__ i1, const int* __restrict__ i2, int M,
    const unsigned short* __restrict__ W1Th, const unsigned short* __restrict__ W1Tl,
    const float* __restrict__ b1,
    const unsigned short* __restrict__ W2Th, const unsigned short* __restrict__ W2Tl,
    const float* __restrict__ b2,
    const float* __restrict__ gamma, const float* __restrict__ beta,
    const float* residual, float* outp,
    float* agg, const int* __restrict__ scat) {
  constexpr int K1 = NSEG * 256;
  __shared__ SM<HLO> sm;

  const int tid = threadIdx.x;
  const int w = tid >> 6;        // wave: owns output cols [w*64, w*64+64)
  const int l = tid & 63;
  const int lr = l & 15;
  const int lg = l >> 4;
  const int colbase = w * 64 + lr;
  const long blockRow = (long)blockIdx.x * 64;

  // staging: thread (w,l) stages row l, k-subchunk w
  const long grow_s = blockRow + l;
  const long growc = grow_s < M ? grow_s : (long)(M - 1);
  const float* rp0 = s0 + growc * Hdim;
  const float* rp1 = nullptr;
  const float* rp2 = nullptr;
  if (NSEG >= 2) rp1 = s1 + (long)(i1 ? i1[growc] : (int)growc) * Hdim;
  if (NSEG >= 3) rp2 = s2 + (long)(i2 ? i2[growc] : (int)growc) * Hdim;

  // ---------------- layer 1: cat(segs) @ W1 (3-product) ----------------
  f32x4 acc[4][4] = {};
  for (int ks = 0; ks < K1 / 32; ++ks) {
    const int seg = ks >> 3;
    const float* rp = rp0;
    if (NSEG >= 2 && seg == 1) rp = rp1;
    if (NSEG >= 3 && seg == 2) rp = rp2;
    __syncthreads();  // prev iteration's LDS reads done
    {
      // B tile: 8 async wave-level copies, dest linear per plane
      const long bcol = (long)(w * 64 + l);
#pragma unroll
      for (int c = 0; c < 4; ++c) {
        GLOAD16(W1Th + bcol * K1 + ks * 32 + c * 8, &sm.bph[c][w * 512]);
        GLOAD16(W1Tl + bcol * K1 + ks * 32 + c * 8, &sm.bpl[c][w * 512]);
      }
      // A tile: gather 32B of row l, split, vector LDS store
      const float* p = rp + (ks & 7) * 32 + w * 8;
      float4 x = *(const float4*)p;
      float4 y = *(const float4*)(p + 4);
      float in[8] = {x.x, x.y, x.z, x.w, y.x, y.y, y.z, y.w};
      u16x8 th, tl;
#pragma unroll
      for (int j = 0; j < 8; ++j) {
        BfPair pr = split2(in[j]);
        th[j] = pr.hi;
        tl[j] = pr.lo;
      }
      *(u16x8*)&sm.ahi[w][l][0] = th;
      *(u16x8*)&sm.alo[w][l][0] = tl;
    }
    __syncthreads();  // drains lgkm + vm (incl. global_load_lds)
    bf16x8 ah[4], al[4], bh[4], bl[4];
#pragma unroll
    for (int rb = 0; rb < 4; ++rb) {
      ah[rb] = *(const bf16x8*)&sm.ahi[lg][rb * 16 + lr][0];
      al[rb] = *(const bf16x8*)&sm.alo[lg][rb * 16 + lr][0];
    }
#pragma unroll
    for (int n = 0; n < 4; ++n) {
      const int col = colbase + n * 16;
      bh[n] = *(const bf16x8*)&sm.bph[lg][col * 8];
      bl[n] = *(const bf16x8*)&sm.bpl[lg][col * 8];
    }
#pragma unroll
    for (int rb = 0; rb < 4; ++rb)
#pragma unroll
      for (int n = 0; n < 4; ++n) {
        acc[rb][n] = __builtin_amdgcn_mfma_f32_16x16x32_bf16(ah[rb], bh[n], acc[rb][n], 0, 0, 0);
        acc[rb][n] = __builtin_amdgcn_mfma_f32_16x16x32_bf16(ah[rb], bl[n], acc[rb][n], 0, 0, 0);
        acc[rb][n] = __builtin_amdgcn_mfma_f32_16x16x32_bf16(al[rb], bh[n], acc[rb][n], 0, 0, 0);
      }
  }

  // ---------------- bias1 + SiLU -> h (swizzled LDS) ----------------
  float bb1[4];
#pragma unroll
  for (int n = 0; n < 4; ++n) bb1[n] = b1[colbase + n * 16];
#pragma unroll
  for (int rb = 0; rb < 4; ++rb) {
#pragma unroll
    for (int n = 0; n < 4; ++n) {
      const int col = colbase + n * 16;
#pragma unroll
      for (int r = 0; r < 4; ++r) {
        const int row = rb * 16 + lg * 4 + r;
        float v = acc[rb][n][r] + bb1[n];
        v = v / (1.0f + expf(-v));
        const int addr = row * 256 + (col ^ hswz(row));
        if constexpr (HLO) {
          BfPair pr = split2(v);
          sm.hh[addr] = pr.hi;
          sm.hl[addr] = pr.lo;
        } else {
          sm.hh[addr] = f2bf(v);
        }
      }
    }
  }

  // ---------------- layer 2: h @ W2 ----------------
  f32x4 acc2[4][4] = {};
  for (int ks = 0; ks < 8; ++ks) {
    __syncthreads();  // h-writes visible (ks=0); prev B reads done (ks>0)
    {
      const long bcol = (long)(w * 64 + l);
#pragma unroll
      for (int c = 0; c < 4; ++c) {
        GLOAD16(W2Th + bcol * 256 + ks * 32 + c * 8, &sm.bph[c][w * 512]);
        GLOAD16(W2Tl + bcol * 256 + ks * 32 + c * 8, &sm.bpl[c][w * 512]);
      }
    }
    __syncthreads();
    bf16x8 ah[4], al[4], bh[4], bl[4];
#pragma unroll
    for (int rb = 0; rb < 4; ++rb) {
      const int row = rb * 16 + lr;
      const int addr = row * 256 + ((ks * 32 + lg * 8) ^ hswz(row));
      ah[rb] = *(const bf16x8*)&sm.hh[addr];
      if constexpr (HLO) al[rb] = *(const bf16x8*)&sm.hl[addr];
    }
#pragma unroll
    for (int n = 0; n < 4; ++n) {
      const int col = colbase + n * 16;
      bh[n] = *(const bf16x8*)&sm.bph[lg][col * 8];
      bl[n] = *(const bf16x8*)&sm.bpl[lg][col * 8];
    }
#pragma unroll
    for (int rb = 0; rb < 4; ++rb)
#pragma unroll
      for (int n = 0; n < 4; ++n) {
        acc2[rb][n] = __builtin_amdgcn_mfma_f32_16x16x32_bf16(ah[rb], bh[n], acc2[rb][n], 0, 0, 0);
        acc2[rb][n] = __builtin_amdgcn_mfma_f32_16x16x32_bf16(ah[rb], bl[n], acc2[rb][n], 0, 0, 0);
        if constexpr (HLO)
          acc2[rb][n] = __builtin_amdgcn_mfma_f32_16x16x32_bf16(al[rb], bh[n], acc2[rb][n], 0, 0, 0);
      }
  }

  // ---------------- LayerNorm in registers (two-pass) + epilogue ----------------
  float bb2[4], gmv[4], btv[4];
#pragma unroll
  for (int n = 0; n < 4; ++n) {
    const int c = colbase + n * 16;
    bb2[n] = b2[c];
    gmv[n] = gamma[c];
    btv[n] = beta[c];
  }
  // pass 1: row sums (each lane: 4 cols; reduce over 16-lane lr group)
  float psum[16];
#pragma unroll
  for (int rb = 0; rb < 4; ++rb)
#pragma unroll
    for (int r = 0; r < 4; ++r) {
      float s = 0.f;
#pragma unroll
      for (int n = 0; n < 4; ++n) s += acc2[rb][n][r] + bb2[n];
      psum[rb * 4 + r] = s;
    }
#pragma unroll
  for (int i = 0; i < 16; ++i) {
    psum[i] += __shfl_xor(psum[i], 1, 64);
    psum[i] += __shfl_xor(psum[i], 2, 64);
    psum[i] += __shfl_xor(psum[i], 4, 64);
    psum[i] += __shfl_xor(psum[i], 8, 64);
  }
  if (lr == 0) {
#pragma unroll
    for (int rb = 0; rb < 4; ++rb)
#pragma unroll
      for (int r = 0; r < 4; ++r)
        sm.lnp[w][rb * 16 + lg * 4 + r][0] = psum[rb * 4 + r];
  }
  __syncthreads();
  float mu[16];
#pragma unroll
  for (int rb = 0; rb < 4; ++rb)
#pragma unroll
    for (int r = 0; r < 4; ++r) {
      const int row = rb * 16 + lg * 4 + r;
      mu[rb * 4 + r] = (sm.lnp[0][row][0] + sm.lnp[1][row][0] +
                        sm.lnp[2][row][0] + sm.lnp[3][row][0]) * (1.0f / 256.0f);
    }
  // pass 2: sum of squared deviations
  float psq[16];
#pragma unroll
  for (int rb = 0; rb < 4; ++rb)
#pragma unroll
    for (int r = 0; r < 4; ++r) {
      float s = 0.f;
#pragma unroll
      for (int n = 0; n < 4; ++n) {
        const float d = acc2[rb][n][r] + bb2[n] - mu[rb * 4 + r];
        s += d * d;
      }
      psq[rb * 4 + r] = s;
    }
#pragma unroll
  for (int i = 0; i < 16; ++i) {
    psq[i] += __shfl_xor(psq[i], 1, 64);
    psq[i] += __shfl_xor(psq[i], 2, 64);
    psq[i] += __shfl_xor(psq[i], 4, 64);
    psq[i] += __shfl_xor(psq[i], 8, 64);
  }
  if (lr == 0) {
#pragma unroll
    for (int rb = 0; rb < 4; ++rb)
#pragma unroll
      for (int r = 0; r < 4; ++r)
        sm.lnp[w][rb * 16 + lg * 4 + r][1] = psq[rb * 4 + r];
  }
  __syncthreads();
#pragma unroll
  for (int rb = 0; rb < 4; ++rb) {
#pragma unroll
    for (int r = 0; r < 4; ++r) {
      const int row = rb * 16 + lg * 4 + r;
      const long grow = blockRow + row;
      if (grow >= M) continue;
      const float var = (sm.lnp[0][row][1] + sm.lnp[1][row][1] +
                         sm.lnp[2][row][1] + sm.lnp[3][row][1]) * (1.0f / 256.0f);
      const float rstd = 1.0f / sqrtf(var + 1e-5f);
      const float m = mu[rb * 4 + r];
      if constexpr (SCATTER) {
        const int d = scat[grow];
        float* ap = agg + (long)d * Hdim;
#pragma unroll
        for (int n = 0; n < 4; ++n) {
          const int c = colbase + n * 16;
          atomicAdd(ap + c, (acc2[rb][n][r] + bb2[n] - m) * rstd * gmv[n] + btv[n]);
        }
      } else {
        const long o = grow * Hdim;
#pragma unroll
        for (int n = 0; n < 4; ++n) {
          const int c = colbase + n * 16;
          outp[o + c] = (acc2[rb][n][r] + bb2[n] - m) * rstd * gmv[n] + btv[n] + residual[o + c];
        }
      }
    }
  }
}

extern "C" void kernel_launch(void* const* d_in, const int* in_sizes, int n_in,
                              void* d_out, int out_size, void* d_ws, size_t ws_size,
                              hipStream_t stream) {
  const float* g2m   = (const float*)d_in[0];
  const float* gridf = (const float*)d_in[1];
  const float* meshf = (const float*)d_in[2];
  const int*   src   = (const int*)d_in[3];
  const int*   dst   = (const int*)d_in[4];
  const float* eW1 = (const float*)d_in[5];  const float* eb1 = (const float*)d_in[6];
  const float* eW2 = (const float*)d_in[7];  const float* eb2 = (const float*)d_in[8];
  const float* eg  = (const float*)d_in[9];  const float* ebt = (const float*)d_in[10];
  const float* sW1 = (const float*)d_in[11]; const float* sb1 = (const float*)d_in[12];
  const float* sW2 = (const float*)d_in[13]; const float* sb2 = (const float*)d_in[14];
  const float* sg  = (const float*)d_in[15]; const float* sbt = (const float*)d_in[16];
  const float* dW1 = (const float*)d_in[17]; const float* db1 = (const float*)d_in[18];
  const float* dW2 = (const float*)d_in[19]; const float* db2 = (const float*)d_in[20];
  const float* dg  = (const float*)d_in[21]; const float* dbt = (const float*)d_in[22];

  float* out_grid = (float*)d_out;
  float* out_mesh = out_grid + (long)NG_N * Hdim;  // doubles as agg accumulator

  // split-bf16 transposed weights in workspace (~2.4 MB)
  unsigned short* p = (unsigned short*)d_ws;
  unsigned short* eW1Th = p; p += 768 * 256;  unsigned short* eW1Tl = p; p += 768 * 256;
  unsigned short* eW2Th = p; p += 256 * 256;  unsigned short* eW2Tl = p; p += 256 * 256;
  unsigned short* sW1Th = p; p += 256 * 256;  unsigned short* sW1Tl = p; p += 256 * 256;
  unsigned short* sW2Th = p; p += 256 * 256;  unsigned short* sW2Tl = p; p += 256 * 256;
  unsigned short* dW1Th = p; p += 512 * 256;  unsigned short* dW1Tl = p; p += 512 * 256;
  unsigned short* dW2Th = p; p += 256 * 256;  unsigned short* dW2Tl = p; p += 256 * 256;

  auto WT = [&](const float* W, unsigned short* Th, unsigned short* Tl, int K, int N) {
    int tot = K * N;
    wtrans_kernel<<<(tot + 255) / 256, 256, 0, stream>>>(W, Th, Tl, K, N);
  };
  WT(eW1, eW1Th, eW1Tl, 768, 256);
  WT(eW2, eW2Th, eW2Tl, 256, 256);
  WT(sW1, sW1Th, sW1Tl, 256, 256);
  WT(sW2, sW2Th, sW2Tl, 256, 256);
  WT(dW1, dW1Th, dW1Tl, 512, 256);
  WT(dW2, dW2Th, dW2Tl, 256, 256);

  // zero the agg accumulator (mesh output region)
  (void)hipMemsetAsync(out_mesh, 0, (size_t)NM_N * Hdim * sizeof(float), stream);

  // edge MLP: cat[g2m, grid[src], mesh[dst]] -> LN -> atomic scatter into agg
  mlp_mfma<3, true, false><<<(E_N + 63) / 64, 256, 0, stream>>>(
      g2m, gridf, meshf, src, dst, E_N,
      eW1Th, eW1Tl, eb1, eW2Th, eW2Tl, eb2, eg, ebt,
      nullptr, nullptr, out_mesh, dst);

  // grid MLP (precision-sensitive: keep h split): grid_new = grid + MLP(grid)
  mlp_mfma<1, false, true><<<(NG_N + 63) / 64, 256, 0, stream>>>(
      gridf, nullptr, nullptr, nullptr, nullptr, NG_N,
      sW1Th, sW1Tl, sb1, sW2Th, sW2Tl, sb2, sg, sbt,
      gridf, out_grid, nullptr, nullptr);

  // mesh MLP: mesh_new = mesh + MLP(cat[agg, mesh])
  mlp_mfma<2, false, false><<<(NM_N + 63) / 64, 256, 0, stream>>>(
      out_mesh, meshf, nullptr, nullptr, nullptr, NM_N,
      dW1Th, dW1Tl, db1, dW2Th, dW2Tl, db2, dg, dbt,
      meshf, out_mesh, nullptr, nullptr);
}

// Round 7
// 1082.855 us; speedup vs baseline: 2.7570x; 1.6377x over previous
//
#include <hip/hip_runtime.h>
#include <math.h>

#define Hdim 256
static const int E_N  = 260640;
static const int NG_N = 65160;
static const int NM_N = 40962;

typedef __attribute__((ext_vector_type(8))) __bf16 bf16x8;
typedef __attribute__((ext_vector_type(8))) unsigned short u16x8;
typedef __attribute__((ext_vector_type(4))) float f32x4;

__device__ __forceinline__ unsigned short f2bf(float f) {
  unsigned u = __float_as_uint(f);
  u = (u + 0x7FFFu + ((u >> 16) & 1u)) >> 16;
  return (unsigned short)u;
}
__device__ __forceinline__ float bf2f(unsigned short h) {
  return __uint_as_float((unsigned)h << 16);
}
struct BfPair { unsigned short hi, lo; };
__device__ __forceinline__ BfPair split2(float f) {
  BfPair r;
  r.hi = f2bf(f);
  r.lo = f2bf(f - bf2f(r.hi));
  return r;
}
// full-rank swizzle for the h tile
__device__ __forceinline__ int hswz(int row) {
  return ((row & 7) << 3) ^ (((row >> 2) & 3) << 4);
}
// LDS-visibility barrier that does NOT drain vmcnt (keeps prefetch in flight)
__device__ __forceinline__ void bar_lds() {
  asm volatile("s_waitcnt lgkmcnt(0)" ::: "memory");
  __builtin_amdgcn_s_barrier();
}

// W [K][N] f32 -> WT_hi/WT_lo [N][K] bf16 split (one-shot pre-pass)
__global__ void wtrans_kernel(const float* __restrict__ W,
                              unsigned short* __restrict__ WThi,
                              unsigned short* __restrict__ WTlo, int K, int N) {
  int i = blockIdx.x * 256 + threadIdx.x;
  if (i >= K * N) return;
  int n = i / K;
  int k = i - n * K;
  BfPair p = split2(W[(long)k * N + n]);
  WThi[i] = p.hi;
  WTlo[i] = p.lo;
}

struct SMem {
  unsigned short ahi[2][4][64][8];  // A chunks dbuf [buf][kgroup][row][8]  8 KB
  unsigned short alo[2][4][64][8];  //                                      8 KB
  unsigned short hh[64 * 256];      // h (bf16 hi), swizzled               32 KB
  float lnp[4][64][2];              // LN partials [wave][row][{s,q}]       2 KB
};                                  // total 50 KB

// out = LN(silu(cat(segs)@W1+b1)@W2+b2)*g+b  [+residual store | atomic scatter]
// layer1: 3-product split-bf16; layer2: 2-product (h-hi x W2-split).
template <int NSEG, bool SCATTER>
__launch_bounds__(256, 2)
__global__ void mlp_mfma(
    const float* s0, const float* s1, const float* s2,
    const int* __restrict__ i1, const int* __restrict__ i2, int M,
    const unsigned short* __restrict__ W1Th, const unsigned short* __restrict__ W1Tl,
    const float* __restrict__ b1,
    const unsigned short* __restrict__ W2Th, const unsigned short* __restrict__ W2Tl,
    const float* __restrict__ b2,
    const float* __restrict__ gamma, const float* __restrict__ beta,
    const float* residual, float* outp,
    float* agg, const int* __restrict__ scat) {
  constexpr int K1 = NSEG * 256;
  constexpr int NT = K1 / 32;
  __shared__ SMem sm;

  const int tid = threadIdx.x;
  const int w = tid >> 6;        // wave: owns output cols [w*64, w*64+64)
  const int l = tid & 63;
  const int lr = l & 15;
  const int lg = l >> 4;
  const int colbase = w * 64 + lr;
  const long blockRow = (long)blockIdx.x * 64;

  // staging: thread (w,l) stages row l, k-subchunk w
  const long grow_s = blockRow + l;
  const long growc = grow_s < M ? grow_s : (long)(M - 1);
  const float* rp0 = s0 + growc * Hdim;
  const float* rp1 = nullptr;
  const float* rp2 = nullptr;
  if (NSEG >= 2) rp1 = s1 + (long)(i1 ? i1[growc] : (int)growc) * Hdim;
  if (NSEG >= 3) rp2 = s2 + (long)(i2 ? i2[growc] : (int)growc) * Hdim;

  auto aptr = [&](int t) -> const float* {
    const int seg = t >> 3;
    const float* rp = rp0;
    if (NSEG >= 2 && seg == 1) rp = rp1;
    if (NSEG >= 3 && seg == 2) rp = rp2;
    return rp + (t & 7) * 32 + w * 8;
  };

  // ---------------- layer 1: cat(segs) @ W1 (3-product, pipelined) ----------------
  f32x4 acc[4][4] = {};
  // prologue: A(0) and B(0) in regs
  float4 a0x = *(const float4*)aptr(0);
  float4 a0y = *(const float4*)(aptr(0) + 4);
  bf16x8 bhc[4], blc[4];
#pragma unroll
  for (int n = 0; n < 4; ++n) {
    const long off = (long)(colbase + n * 16) * K1 + lg * 8;
    bhc[n] = *(const bf16x8*)(W1Th + off);
    blc[n] = *(const bf16x8*)(W1Tl + off);
  }

  for (int t = 0; t < NT; ++t) {
    const int tn = (t + 1 < NT) ? t + 1 : t;
    // 1. issue prefetch for t+1 (stays in flight across the barrier)
    const float* pn = aptr(tn);
    float4 a1x = *(const float4*)pn;
    float4 a1y = *(const float4*)(pn + 4);
    bf16x8 bhn[4], bln[4];
#pragma unroll
    for (int n = 0; n < 4; ++n) {
      const long off = (long)(colbase + n * 16) * K1 + tn * 32 + lg * 8;
      bhn[n] = *(const bf16x8*)(W1Th + off);
      bln[n] = *(const bf16x8*)(W1Tl + off);
    }
    // 2. convert + ds_write A(t) into buf[t&1]
    {
      float in[8] = {a0x.x, a0x.y, a0x.z, a0x.w, a0y.x, a0y.y, a0y.z, a0y.w};
      u16x8 th, tl;
#pragma unroll
      for (int j = 0; j < 8; ++j) {
        BfPair pr = split2(in[j]);
        th[j] = pr.hi;
        tl[j] = pr.lo;
      }
      *(u16x8*)&sm.ahi[t & 1][w][l][0] = th;
      *(u16x8*)&sm.alo[t & 1][w][l][0] = tl;
    }
    // 3. LDS-only barrier (no vmcnt drain)
    bar_lds();
    // 4. fragments + MFMA
    bf16x8 ah[4], al[4];
#pragma unroll
    for (int rb = 0; rb < 4; ++rb) {
      ah[rb] = *(const bf16x8*)&sm.ahi[t & 1][lg][rb * 16 + lr][0];
      al[rb] = *(const bf16x8*)&sm.alo[t & 1][lg][rb * 16 + lr][0];
    }
#pragma unroll
    for (int rb = 0; rb < 4; ++rb)
#pragma unroll
      for (int n = 0; n < 4; ++n) {
        acc[rb][n] = __builtin_amdgcn_mfma_f32_16x16x32_bf16(ah[rb], bhc[n], acc[rb][n], 0, 0, 0);
        acc[rb][n] = __builtin_amdgcn_mfma_f32_16x16x32_bf16(ah[rb], bln[0 ? 0 : n] * 0 + blc[n], acc[rb][n], 0, 0, 0);
        acc[rb][n] = __builtin_amdgcn_mfma_f32_16x16x32_bf16(al[rb], bhc[n], acc[rb][n], 0, 0, 0);
      }
    // 5. rotate
    a0x = a1x; a0y = a1y;
#pragma unroll
    for (int n = 0; n < 4; ++n) { bhc[n] = bhn[n]; blc[n] = bln[n]; }
  }

  // issue B2(0) prefetch early (hides under SiLU + h-store)
  bf16x8 b2hc[4], b2lc[4];
#pragma unroll
  for (int n = 0; n < 4; ++n) {
    const long off = (long)(colbase + n * 16) * 256 + lg * 8;
    b2hc[n] = *(const bf16x8*)(W2Th + off);
    b2lc[n] = *(const bf16x8*)(W2Tl + off);
  }

  // ---------------- bias1 + SiLU -> h (bf16 hi, swizzled) ----------------
  float bb1[4];
#pragma unroll
  for (int n = 0; n < 4; ++n) bb1[n] = b1[colbase + n * 16];
#pragma unroll
  for (int rb = 0; rb < 4; ++rb) {
#pragma unroll
    for (int n = 0; n < 4; ++n) {
      const int col = colbase + n * 16;
#pragma unroll
      for (int r = 0; r < 4; ++r) {
        const int row = rb * 16 + lg * 4 + r;
        float v = acc[rb][n][r] + bb1[n];
        v = v / (1.0f + expf(-v));
        sm.hh[row * 256 + (col ^ hswz(row))] = f2bf(v);
      }
    }
  }
  bar_lds();

  // ---------------- layer 2: h @ W2 (2-product, no barriers) ----------------
  f32x4 acc2[4][4] = {};
  for (int ks = 0; ks < 8; ++ks) {
    const int kn = (ks + 1 < 8) ? ks + 1 : ks;
    bf16x8 b2hn[4], b2ln[4];
#pragma unroll
    for (int n = 0; n < 4; ++n) {
      const long off = (long)(colbase + n * 16) * 256 + kn * 32 + lg * 8;
      b2hn[n] = *(const bf16x8*)(W2Th + off);
      b2ln[n] = *(const bf16x8*)(W2Tl + off);
    }
    bf16x8 ah[4];
#pragma unroll
    for (int rb = 0; rb < 4; ++rb) {
      const int row = rb * 16 + lr;
      ah[rb] = *(const bf16x8*)&sm.hh[row * 256 + ((ks * 32 + lg * 8) ^ hswz(row))];
    }
#pragma unroll
    for (int rb = 0; rb < 4; ++rb)
#pragma unroll
      for (int n = 0; n < 4; ++n) {
        acc2[rb][n] = __builtin_amdgcn_mfma_f32_16x16x32_bf16(ah[rb], b2hc[n], acc2[rb][n], 0, 0, 0);
        acc2[rb][n] = __builtin_amdgcn_mfma_f32_16x16x32_bf16(ah[rb], b2lc[n], acc2[rb][n], 0, 0, 0);
      }
#pragma unroll
    for (int n = 0; n < 4; ++n) { b2hc[n] = b2hn[n]; b2lc[n] = b2ln[n]; }
  }

  // ---------------- LayerNorm in registers (two-pass) + epilogue ----------------
  float bb2[4], gmv[4], btv[4];
#pragma unroll
  for (int n = 0; n < 4; ++n) {
    const int c = colbase + n * 16;
    bb2[n] = b2[c];
    gmv[n] = gamma[c];
    btv[n] = beta[c];
  }
  float psum[16];
#pragma unroll
  for (int rb = 0; rb < 4; ++rb)
#pragma unroll
    for (int r = 0; r < 4; ++r) {
      float s = 0.f;
#pragma unroll
      for (int n = 0; n < 4; ++n) s += acc2[rb][n][r] + bb2[n];
      psum[rb * 4 + r] = s;
    }
#pragma unroll
  for (int i = 0; i < 16; ++i) {
    psum[i] += __shfl_xor(psum[i], 1, 64);
    psum[i] += __shfl_xor(psum[i], 2, 64);
    psum[i] += __shfl_xor(psum[i], 4, 64);
    psum[i] += __shfl_xor(psum[i], 8, 64);
  }
  if (lr == 0) {
#pragma unroll
    for (int rb = 0; rb < 4; ++rb)
#pragma unroll
      for (int r = 0; r < 4; ++r)
        sm.lnp[w][rb * 16 + lg * 4 + r][0] = psum[rb * 4 + r];
  }
  __syncthreads();
  float mu[16];
#pragma unroll
  for (int rb = 0; rb < 4; ++rb)
#pragma unroll
    for (int r = 0; r < 4; ++r) {
      const int row = rb * 16 + lg * 4 + r;
      mu[rb * 4 + r] = (sm.lnp[0][row][0] + sm.lnp[1][row][0] +
                        sm.lnp[2][row][0] + sm.lnp[3][row][0]) * (1.0f / 256.0f);
    }
  float psq[16];
#pragma unroll
  for (int rb = 0; rb < 4; ++rb)
#pragma unroll
    for (int r = 0; r < 4; ++r) {
      float s = 0.f;
#pragma unroll
      for (int n = 0; n < 4; ++n) {
        const float d = acc2[rb][n][r] + bb2[n] - mu[rb * 4 + r];
        s += d * d;
      }
      psq[rb * 4 + r] = s;
    }
#pragma unroll
  for (int i = 0; i < 16; ++i) {
    psq[i] += __shfl_xor(psq[i], 1, 64);
    psq[i] += __shfl_xor(psq[i], 2, 64);
    psq[i] += __shfl_xor(psq[i], 4, 64);
    psq[i] += __shfl_xor(psq[i], 8, 64);
  }
  if (lr == 0) {
#pragma unroll
    for (int rb = 0; rb < 4; ++rb)
#pragma unroll
      for (int r = 0; r < 4; ++r)
        sm.lnp[w][rb * 16 + lg * 4 + r][1] = psq[rb * 4 + r];
  }
  __syncthreads();
#pragma unroll
  for (int rb = 0; rb < 4; ++rb) {
#pragma unroll
    for (int r = 0; r < 4; ++r) {
      const int row = rb * 16 + lg * 4 + r;
      const long grow = blockRow + row;
      if (grow >= M) continue;
      const float var = (sm.lnp[0][row][1] + sm.lnp[1][row][1] +
                         sm.lnp[2][row][1] + sm.lnp[3][row][1]) * (1.0f / 256.0f);
      const float rstd = 1.0f / sqrtf(var + 1e-5f);
      const float m = mu[rb * 4 + r];
      if constexpr (SCATTER) {
        const int d = scat[grow];
        float* ap = agg + (long)d * Hdim;
#pragma unroll
        for (int n = 0; n < 4; ++n) {
          const int c = colbase + n * 16;
          atomicAdd(ap + c, (acc2[rb][n][r] + bb2[n] - m) * rstd * gmv[n] + btv[n]);
        }
      } else {
        const long o = grow * Hdim;
#pragma unroll
        for (int n = 0; n < 4; ++n) {
          const int c = colbase + n * 16;
          outp[o + c] = (acc2[rb][n][r] + bb2[n] - m) * rstd * gmv[n] + btv[n] + residual[o + c];
        }
      }
    }
  }
}

extern "C" void kernel_launch(void* const* d_in, const int* in_sizes, int n_in,
                              void* d_out, int out_size, void* d_ws, size_t ws_size,
                              hipStream_t stream) {
  const float* g2m   = (const float*)d_in[0];
  const float* gridf = (const float*)d_in[1];
  const float* meshf = (const float*)d_in[2];
  const int*   src   = (const int*)d_in[3];
  const int*   dst   = (const int*)d_in[4];
  const float* eW1 = (const float*)d_in[5];  const float* eb1 = (const float*)d_in[6];
  const float* eW2 = (const float*)d_in[7];  const float* eb2 = (const float*)d_in[8];
  const float* eg  = (const float*)d_in[9];  const float* ebt = (const float*)d_in[10];
  const float* sW1 = (const float*)d_in[11]; const float* sb1 = (const float*)d_in[12];
  const float* sW2 = (const float*)d_in[13]; const float* sb2 = (const float*)d_in[14];
  const float* sg  = (const float*)d_in[15]; const float* sbt = (const float*)d_in[16];
  const float* dW1 = (const float*)d_in[17]; const float* db1 = (const float*)d_in[18];
  const float* dW2 = (const float*)d_in[19]; const float* db2 = (const float*)d_in[20];
  const float* dg  = (const float*)d_in[21]; const float* dbt = (const float*)d_in[22];

  float* out_grid = (float*)d_out;
  float* out_mesh = out_grid + (long)NG_N * Hdim;  // doubles as agg accumulator

  // split-bf16 transposed weights in workspace (~2.4 MB)
  unsigned short* p = (unsigned short*)d_ws;
  unsigned short* eW1Th = p; p += 768 * 256;  unsigned short* eW1Tl = p; p += 768 * 256;
  unsigned short* eW2Th = p; p += 256 * 256;  unsigned short* eW2Tl = p; p += 256 * 256;
  unsigned short* sW1Th = p; p += 256 * 256;  unsigned short* sW1Tl = p; p += 256 * 256;
  unsigned short* sW2Th = p; p += 256 * 256;  unsigned short* sW2Tl = p; p += 256 * 256;
  unsigned short* dW1Th = p; p += 512 * 256;  unsigned short* dW1Tl = p; p += 512 * 256;
  unsigned short* dW2Th = p; p += 256 * 256;  unsigned short* dW2Tl = p; p += 256 * 256;

  auto WT = [&](const float* W, unsigned short* Th, unsigned short* Tl, int K, int N) {
    int tot = K * N;
    wtrans_kernel<<<(tot + 255) / 256, 256, 0, stream>>>(W, Th, Tl, K, N);
  };
  WT(eW1, eW1Th, eW1Tl, 768, 256);
  WT(eW2, eW2Th, eW2Tl, 256, 256);
  WT(sW1, sW1Th, sW1Tl, 256, 256);
  WT(sW2, sW2Th, sW2Tl, 256, 256);
  WT(dW1, dW1Th, dW1Tl, 512, 256);
  WT(dW2, dW2Th, dW2Tl, 256, 256);

  // zero the agg accumulator (mesh output region)
  (void)hipMemsetAsync(out_mesh, 0, (size_t)NM_N * Hdim * sizeof(float), stream);

  // edge MLP: cat[g2m, grid[src], mesh[dst]] -> LN -> atomic scatter into agg
  mlp_mfma<3, true><<<(E_N + 63) / 64, 256, 0, stream>>>(
      g2m, gridf, meshf, src, dst, E_N,
      eW1Th, eW1Tl, eb1, eW2Th, eW2Tl, eb2, eg, ebt,
      nullptr, nullptr, out_mesh, dst);

  // grid MLP: grid_new = grid + MLP(grid)
  mlp_mfma<1, false><<<(NG_N + 63) / 64, 256, 0, stream>>>(
      gridf, nullptr, nullptr, nullptr, nullptr, NG_N,
      sW1Th, sW1Tl, sb1, sW2Th, sW2Tl, sb2, sg, sbt,
      gridf, out_grid, nullptr, nullptr);

  // mesh MLP: mesh_new = mesh + MLP(cat[agg, mesh])
  mlp_mfma<2, false><<<(NM_N + 63) / 64, 256, 0, stream>>>(
      out_mesh, meshf, nullptr, nullptr, nullptr, NM_N,
      dW1Th, dW1Tl, db1, dW2Th, dW2Tl, db2, dg, dbt,
      meshf, out_mesh, nullptr, nullptr);
}